// Round 8
// baseline (218.352 us; speedup 1.0000x reference)
//
#include <hip/hip_runtime.h>
#include <hip/hip_bf16.h>

// Problem constants
#define LNUM 8
#define ENUM 8
#define DDIM 256
#define BSZ  16384
#define H1N  64
#define H2N  32

#define BT   32     // rows per block (small => grid 512 => 2 blocks/CU)
#define NTHR 256    // 4 waves

#define PH1  72     // h1T row pitch (u16)
#define PH2  40     // h2T row pitch (u16)
#define PSW  9      // softmax pitch (floats)

// ws element offsets (u16) for fragment-ordered weights (frag = 1 KB linear)
#define WS1_OFF 0           // 64 steps * 16384
#define WS2_OFF 1048576     // 64 steps * 2048
#define WS3_OFF 1179648     // 64 steps * 8192

typedef float f32x4 __attribute__((ext_vector_type(4)));
typedef unsigned short u16x8 __attribute__((ext_vector_type(8)));
typedef unsigned short u16x4 __attribute__((ext_vector_type(4)));
typedef __bf16 bf16x8 __attribute__((ext_vector_type(8)));

#define Z4 ((f32x4){0.f, 0.f, 0.f, 0.f})

// Round-to-nearest-even f32 -> bf16 (truncation bias compounds over 24 GEMMs).
static __device__ __forceinline__ unsigned short f2bf(float f) {
    unsigned u = __builtin_bit_cast(unsigned, f);
    u += 0x7fffu + ((u >> 16) & 1u);
    return (unsigned short)(u >> 16);
}

static __device__ __forceinline__ f32x4 mfma16(u16x8 a, u16x8 b, f32x4 c) {
    return __builtin_amdgcn_mfma_f32_16x16x32_bf16(
        __builtin_bit_cast(bf16x8, a), __builtin_bit_cast(bf16x8, b), c, 0, 0, 0);
}

// ---------------------------------------------------------------------------
// Kernel 1: fp32 weights -> bf16 B-fragment layout (unchanged from R7).
// Fragment slot (q*16+r) holds W[n0+r][k0+q*8 .. +7]; frag = 1 KB linear.
//   ws1: [s][nt(4)][kt(8)][512]  ws2: [s][n2(2)][kt(2)][512]  ws3: [s][nt(16)][512]
// ---------------------------------------------------------------------------
__global__ __launch_bounds__(256) void cvt_w_frag(
    const float* __restrict__ w1, const float* __restrict__ w2,
    const float* __restrict__ w3, unsigned short* __restrict__ ws)
{
    int gid = blockIdx.x * 256 + threadIdx.x;
    const float* src;
    if (gid < 131072) {                          // W1: [s][n(64)][k(256)]
        int s = gid >> 11, o = gid & 2047;
        int f = o >> 6, lane = o & 63;
        int n = (f >> 3) * 16 + (lane & 15), k = (f & 7) * 32 + (lane >> 4) * 8;
        src = w1 + ((size_t)s * 16384 + n * 256 + k);
    } else if (gid < 147456) {                   // W2: [s][n(32)][k(64)]
        int g = gid - 131072;
        int s = g >> 8, o = g & 255;
        int f = o >> 6, lane = o & 63;
        int n = (f >> 1) * 16 + (lane & 15), k = (f & 1) * 32 + (lane >> 4) * 8;
        src = w2 + ((size_t)s * 2048 + n * 64 + k);
    } else {                                     // W3: [s][n(256)][k(32)]
        int g = gid - 147456;
        int s = g >> 10, o = g & 1023;
        int f = o >> 6, lane = o & 63;
        int n = f * 16 + (lane & 15), k = (lane >> 4) * 8;
        src = w3 + ((size_t)s * 8192 + n * 32 + k);
    }
    float4 a = *(const float4*)src;
    float4 b = *(const float4*)(src + 4);
    u16x8 p;
    p[0] = f2bf(a.x); p[1] = f2bf(a.y); p[2] = f2bf(a.z); p[3] = f2bf(a.w);
    p[4] = f2bf(b.x); p[5] = f2bf(b.y); p[6] = f2bf(b.z); p[7] = f2bf(b.w);
    *(u16x8*)(ws + (size_t)gid * 8) = p;         // coalesced
}

// ---------------------------------------------------------------------------
// Kernel 2: fused 8-layer x 8-expert MoE MLP.
// BT=32, 4 waves, grid 512 -> 2 blocks/CU: two INDEPENDENT barrier domains
// per CU, so one block's barrier+vmcnt drains overlap the other's compute
// (the 1-block convoy was the R4/R5/R7 ~130-145us plateau). Weights are read
// directly from global in frag layout -- duplication-free wave splits keep
// per-CU L1 traffic at ~47us busy, the new floor. LDS carries only the tiny
// h1/h2 transposes + swizzled x exchange (24.7 KB/block).
// Wave w: G1 feats [w*16,w*16+16) x all 32 rows; G2 feat-tile (w>>1) x
// row-tile (w&1); G3 cols [w*64,w*64+64) x all 32 rows.
// ---------------------------------------------------------------------------
__global__ __launch_bounds__(NTHR, 2) void moe_fused(
    const float* __restrict__ src, const unsigned short* __restrict__ Wf,
    const float* __restrict__ b1, const float* __restrict__ b2,
    const float* __restrict__ b3, const float* __restrict__ masks,
    float* __restrict__ out)
{
    __shared__ __align__(16) unsigned short X[BT * 256];      // 16384 B (XOR-swizzled)
    __shared__ __align__(16) unsigned short H1T[BT * PH1];    //  4608 B [row][feat]
    __shared__ __align__(16) unsigned short H2T[BT * PH2];    //  2560 B [row][feat]
    __shared__ float SW[BT * PSW];                            //  1152 B
    // total 24704 B -> 2 blocks/CU (LDS-wise up to 6)

    const int tid  = threadIdx.x;
    const int lane = tid & 63;
    const int w    = tid >> 6;      // {0..3}
    const int wq   = w >> 1;        // G2 feat group {0,1}
    const int wr   = w & 1;         // G2 row tile {0,1}
    const int n15  = lane & 15;
    const int q    = lane >> 4;
    const int b0   = blockIdx.x * BT;

    u16x8 xf[2][8];      // persistent x B-frags: ALL 32 rows (2 mt), K=256
    f32x4 ACC[2][4];     // rows (2 mt) x cols w*64 (4 nt)

    auto stage_softmax = [&](int l) {
        if (tid < BT) {
            const float* mp = masks + ((size_t)l * BSZ + b0 + tid) * ENUM;
            float4 m0 = *(const float4*)mp;
            float4 m1 = *(const float4*)(mp + 4);
            float mv[8] = {m0.x, m0.y, m0.z, m0.w, m1.x, m1.y, m1.z, m1.w};
            float mx = mv[0];
            #pragma unroll
            for (int e = 1; e < 8; ++e) mx = fmaxf(mx, mv[e]);
            float s = 0.f;
            #pragma unroll
            for (int e = 0; e < 8; ++e) { mv[e] = expf(mv[e] - mx); s += mv[e]; }
            float inv = 1.f / s;
            #pragma unroll
            for (int e = 0; e < 8; ++e) SW[tid * PSW + e] = mv[e] * inv;
        }
    };

    // ACC = sum_e softmax_w[row][e] * b3[e][col]  (fp32 VALU, once per layer)
    auto acc_init = [&](int l) {
        const float* b3l = b3 + (size_t)l * ENUM * DDIM;
        #pragma unroll
        for (int mt = 0; mt < 2; ++mt)
            #pragma unroll
            for (int nt = 0; nt < 4; ++nt) ACC[mt][nt] = Z4;
        #pragma unroll 2
        for (int e2 = 0; e2 < ENUM; ++e2) {
            float swv[2][4];
            #pragma unroll
            for (int mt = 0; mt < 2; ++mt)
                #pragma unroll
                for (int rg = 0; rg < 4; ++rg)
                    swv[mt][rg] = SW[(mt*16 + q*4 + rg) * PSW + e2];
            #pragma unroll
            for (int nt = 0; nt < 4; ++nt) {
                float bv = b3l[e2 * DDIM + w*64 + nt*16 + n15];
                #pragma unroll
                for (int mt = 0; mt < 2; ++mt)
                    #pragma unroll
                    for (int rg = 0; rg < 4; ++rg)
                        ACC[mt][nt][rg] += swv[mt][rg] * bv;
            }
        }
    };

    // x exchange: XOR granule swizzle over pitch-256 rows -> conflict-free
    auto xf_read = [&]() {
        #pragma unroll
        for (int mt = 0; mt < 2; ++mt)
            #pragma unroll
            for (int kt = 0; kt < 8; ++kt) {
                int row  = mt*16 + n15;
                int phys = (kt*4 + q) ^ (row & 31);
                xf[mt][kt] = *(const u16x8*)&X[row*256 + phys*8];
            }
    };
    auto x_write = [&]() {
        #pragma unroll
        for (int mt = 0; mt < 2; ++mt)
            #pragma unroll
            for (int nt = 0; nt < 4; ++nt)
                #pragma unroll
                for (int rg = 0; rg < 4; ++rg) {
                    int row  = mt*16 + q*4 + rg;
                    int col  = w*64 + nt*16 + n15;
                    int phys = (col >> 3) ^ (row & 31);
                    X[row*256 + phys*8 + (col & 7)] = f2bf(ACC[mt][nt][rg]);
                }
    };

    // ================= prologue =================
    #pragma unroll
    for (int i = 0; i < 4; ++i) {                // layer-0 x -> X (swizzled)
        int o = (i * NTHR + tid) * 8;            // 32x256 elems
        int r = o >> 8, c = o & 255;
        const float* p = src + (size_t)(b0 + r) * DDIM + c;
        float4 f0 = *(const float4*)(p);
        float4 f1 = *(const float4*)(p + 4);
        u16x8 pk;
        pk[0] = f2bf(f0.x); pk[1] = f2bf(f0.y); pk[2] = f2bf(f0.z); pk[3] = f2bf(f0.w);
        pk[4] = f2bf(f1.x); pk[5] = f2bf(f1.y); pk[6] = f2bf(f1.z); pk[7] = f2bf(f1.w);
        int phys = (c >> 3) ^ (r & 31);
        *(u16x8*)&X[r*256 + phys*8] = pk;
    }
    stage_softmax(0);
    __syncthreads();
    xf_read();
    acc_init(0);

    // ================= expert-step loop =================
    #pragma unroll 1
    for (int s = 0; s < LNUM * ENUM; ++s) {
        const int e = s & 7, l = s >> 3;
        const unsigned short* w1p = Wf + WS1_OFF + (size_t)s * 16384 + w * 4096 + lane * 8;
        const unsigned short* w2p = Wf + WS2_OFF + (size_t)s * 2048 + wq * 1024 + lane * 8;
        const unsigned short* w3p = Wf + WS3_OFF + (size_t)s * 8192 + w * 2048 + lane * 8;

        // ---- G1 (transposed): 16 feats x 32 rows; 4 indep 4-deep chains ----
        u16x8 wf[8];
        #pragma unroll
        for (int kt = 0; kt < 8; ++kt)
            wf[kt] = *(const u16x8*)(w1p + kt * 512);
        u16x8 w2f[2];                              // issue early (used post-B1)
        w2f[0] = *(const u16x8*)(w2p);
        w2f[1] = *(const u16x8*)(w2p + 512);

        f32x4 a1a[2] = {Z4, Z4}, a1b[2] = {Z4, Z4};
        #pragma unroll
        for (int kt = 0; kt < 4; ++kt) {
            a1a[0] = mfma16(wf[kt],     xf[0][kt],     a1a[0]);
            a1a[1] = mfma16(wf[kt],     xf[1][kt],     a1a[1]);
            a1b[0] = mfma16(wf[kt + 4], xf[0][kt + 4], a1b[0]);
            a1b[1] = mfma16(wf[kt + 4], xf[1][kt + 4], a1b[1]);
        }
        {
            float4 bb1 = *(const float4*)(b1 + s * 64 + w * 16 + q * 4);
            #pragma unroll
            for (int mt = 0; mt < 2; ++mt) {
                u16x4 pk;
                #pragma unroll
                for (int rg = 0; rg < 4; ++rg)
                    pk[rg] = f2bf(fmaxf(a1a[mt][rg] + a1b[mt][rg] + bb1[rg], 0.f));
                *(u16x4*)&H1T[(mt*16 + n15) * PH1 + w*16 + q*4] = pk;
            }
        }
        __syncthreads();                           // B1: h1 ready

        // ---- G3's W3 frags issued here: window = G2 + other block's compute ----
        u16x8 w3f[4];
        #pragma unroll
        for (int nt = 0; nt < 4; ++nt)
            w3f[nt] = *(const u16x8*)(w3p + nt * 512);

        // ---- G2 (transposed): feat-tile wq x row-tile wr ----
        f32x4 a2 = Z4;
        {
            u16x8 h0 = *(const u16x8*)&H1T[(wr*16 + n15) * PH1 + q*8];
            u16x8 h1v = *(const u16x8*)&H1T[(wr*16 + n15) * PH1 + q*8 + 32];
            a2 = mfma16(w2f[0], h0, a2);
            a2 = mfma16(w2f[1], h1v, a2);
        }
        {
            float4 bb2 = *(const float4*)(b2 + s * 32 + wq * 16 + q * 4);
            int row = wr*16 + n15;
            float sw = SW[row * PSW + e];
            u16x4 pk;
            #pragma unroll
            for (int rg = 0; rg < 4; ++rg)
                pk[rg] = f2bf(fmaxf(a2[rg] + bb2[rg], 0.f) * sw);
            *(u16x4*)&H2T[row * PH2 + wq*16 + q*4] = pk;
        }
        __syncthreads();                           // B2: h2 ready

        // ---- G3: ACC += h2 @ W3^T (cols w*64, all 32 rows; 8 indep MFMA) ----
        {
            u16x8 g0 = *(const u16x8*)&H2T[(n15) * PH2 + q*8];
            u16x8 g1v = *(const u16x8*)&H2T[(16 + n15) * PH2 + q*8];
            #pragma unroll
            for (int nt = 0; nt < 4; ++nt) {
                ACC[0][nt] = mfma16(g0, w3f[nt], ACC[0][nt]);
                ACC[1][nt] = mfma16(g1v, w3f[nt], ACC[1][nt]);
            }
        }

        // ---- layer transition ----
        if (e == 7 && l < LNUM - 1) {
            __syncthreads();                       // all G3 h2 reads done
            x_write();
            __syncthreads();                       // T1: x visible
            xf_read();
            stage_softmax(l + 1);
            __syncthreads();                       // T2: xf read done, SW ready
            acc_init(l + 1);
        }
    }

    // ================= final store (fp32) =================
    #pragma unroll
    for (int mt = 0; mt < 2; ++mt)
        #pragma unroll
        for (int nt = 0; nt < 4; ++nt)
            #pragma unroll
            for (int rg = 0; rg < 4; ++rg)
                out[(size_t)(b0 + mt*16 + q*4 + rg) * DDIM
                    + w*64 + nt*16 + n15] = ACC[mt][nt][rg];
}

extern "C" void kernel_launch(void* const* d_in, const int* in_sizes, int n_in,
                              void* d_out, int out_size, void* d_ws, size_t ws_size,
                              hipStream_t stream) {
    const float* src   = (const float*)d_in[0];
    const float* W1    = (const float*)d_in[1];
    const float* b1    = (const float*)d_in[2];
    const float* W2    = (const float*)d_in[3];
    const float* b2    = (const float*)d_in[4];
    const float* W3    = (const float*)d_in[5];
    const float* b3    = (const float*)d_in[6];
    const float* masks = (const float*)d_in[7];
    float* out = (float*)d_out;
    unsigned short* ws = (unsigned short*)d_ws;   // needs 3,407,872 B

    hipLaunchKernelGGL(cvt_w_frag, dim3(832), dim3(256), 0, stream, W1, W2, W3, ws);
    hipLaunchKernelGGL(moe_fused, dim3(BSZ / BT), dim3(NTHR), 0, stream,
                       src, ws, b1, b2, b3, masks, out);
}